// Round 6
// baseline (136.541 us; speedup 1.0000x reference)
//
#include <hip/hip_runtime.h>
#include <hip/hip_bf16.h>
#include <math.h>

// Corr: B=4, C=256, H=W=64, HW=4096, TOPK=3, rat_s=0.05 -> sigma=3.2, 2*sigma^2=20.48
// s[m,n] = alpha * (1 - exp(-(dr^2+dc^2)/20.48)) * <xn_m, xn_n>  (symmetric)
// xc[m,n] = exp(2 s[m,n]) / (sm[m] sm[n]),  sm[m] = sum_n exp(s[m,n])
// out[b,k,col] = top-3 over m of xc[m,col]
//
// R1..R9 (proven, 155us): XCD<->batch binding, log-domain top-k, non-atomic
//   partials, k-slot swizzle, triangular dual-direction topk, __syncthreads
//   K-loop, odd-stride rtop, LDS-transposed norm.
// R13 (proven, 140us): single-GEMM pipeline; rowsum stores p2 tiles as fp16;
//   topk GEMM recompute replaced by streaming selector.
// BANNED (measured): raw vmcnt barriers w/ LDS-DMA (R7), cooperative launch
//   (R10), spin barriers (R11), per-block device fences (R12) — the last two
//   poison the XCD L2 via coherence invalidations.
//   R14: per-lane direct-from-L2 MFMA fragment loads — 87us (latency exposed).
//   R15: BK=64 — NULL (barrier count not the limiter; +35% VALU also NULL).
//   R16: 2-tiles-per-block — WORSE (59.5): halved TLP, worse L2 locality.
//   R17: nt store + nt load — total 136.5 (BEST) but rowsum 49.5->58:
//   nt STORE path costs rowsum ~8.5us (HBM-ack epilogue tail at residency
//   ~1.3); downstream gained ~12us. FETCH 9.5->8.26MB confirms less L2
//   pollution. Ambiguous whether downstream gain = nt loads (topsel
//   self-thrash avoidance) or nt stores (clean L2, no writeback evictions).
// R18 (this round): attribution A/B — regular sbuf stores (recover rowsum
//   49.5) + KEEP nt loads in topsel. If total ~127-131: nt-load was the gain
//   (keep this). If total ~140: nt-store was the gain (revert to R17 config).

#define HW 4096
#define CDIM 256
#define INV2S2 0.048828125f  // 1/20.48
#define NEGINF -1e30f
#define NTILE 528
#define LOG2E 1.4426950408889634f

#if defined(__has_builtin)
#  if __has_builtin(__builtin_amdgcn_exp2f)
#    define EXP2F(x) __builtin_amdgcn_exp2f(x)
#  else
#    define EXP2F(x) exp2f(x)
#  endif
#else
#  define EXP2F(x) exp2f(x)
#endif

typedef __bf16 bf16;
typedef _Float16 f16;
typedef __attribute__((ext_vector_type(8))) __bf16 bf16x8;
typedef __attribute__((ext_vector_type(4))) _Float16 f16x4;
typedef __attribute__((ext_vector_type(4))) float f32x4;

#define GAS __attribute__((address_space(1)))
#define LAS __attribute__((address_space(3)))

__device__ __forceinline__ void ins3(float v, float& t0, float& t1, float& t2) {
    // maintains t0>=t1>=t2; exact top-3 insert in 3 VALU ops (v_max + 2x v_med3)
    float n0 = fmaxf(t0, v);
    float n1 = __builtin_amdgcn_fmed3f(t0, t1, v);
    float n2 = __builtin_amdgcn_fmed3f(t1, t2, v);
    t0 = n0; t1 = n1; t2 = n2;
}

// triangular decode: t = mt*(mt+1)/2 + nt, nt <= mt
__device__ __forceinline__ void decode_tri(int t, int& mt, int& nt) {
    int m = (int)((sqrtf(8.f * (float)t + 1.f) - 1.f) * 0.5f);
    while ((m + 1) * (m + 2) / 2 <= t) ++m;
    while (m * (m + 1) / 2 > t) --m;
    mt = m;
    nt = t - m * (m + 1) / 2;
}

// ---------------- normalize + transpose to bf16 xnT[b][pixel][channel] ----------------
__global__ __launch_bounds__(256) void corr_norm(const float* __restrict__ x,
                                                 bf16* __restrict__ xnT) {
    __shared__ float red[4][64];
    __shared__ float invn[64];
    __shared__ __align__(16) bf16 T[64][264];  // 264 = 256 + 8 pad
    int tid = threadIdx.x;
    int pl = tid & 63, cg = tid >> 6;
    int P0 = blockIdx.x * 64;
    int P = P0 + pl;
    int b = P >> 12;
    int pix = P & 4095;
    const float* xb = x + ((size_t)(b * CDIM + cg * 64) << 12) + pix;
    float v[64];
    float ss = 0.f;
#pragma unroll
    for (int j = 0; j < 64; ++j) {
        v[j] = xb[(size_t)j << 12];
        ss += v[j] * v[j];
    }
    red[cg][pl] = ss;
    __syncthreads();
    if (tid < 64) {
        float s = red[0][tid] + red[1][tid] + red[2][tid] + red[3][tid];
        invn[tid] = 1.0f / fmaxf(sqrtf(s), 1e-12f);
    }
    __syncthreads();
    float inv = invn[pl];
#pragma unroll
    for (int j0 = 0; j0 < 64; j0 += 8) {
        bf16x8 pk;
#pragma unroll
        for (int j = 0; j < 8; ++j) pk[j] = (bf16)(v[j0 + j] * inv);
        *(bf16x8*)(&T[pl][cg * 64 + j0]) = pk;
    }
    __syncthreads();
#pragma unroll
    for (int it = 0; it < 8; ++it) {
        int p = it * 8 + (tid >> 5);
        int k = tid & 31;
        bf16x8 val = *(const bf16x8*)(&T[p][k * 8]);
        *(bf16x8*)(xnT + (size_t)(P0 + p) * CDIM + k * 8) = val;
    }
}

// ---------------- GEMM tile core: 128x128, K=256, dbuf single-barrier, k-slot swizzle ----
__device__ __forceinline__ void gemm_tile(const bf16* __restrict__ xb, int mbase, int nbase,
                                          bf16* As, bf16* Bs, f32x4 (&acc)[4][4]) {
    const int tid = threadIdx.x;
    const int wave = tid >> 6;
    const int lane = tid & 63;
    const int wm = wave >> 1, wn = wave & 1;
    const int l15 = lane & 15, quad = lane >> 4;
#pragma unroll
    for (int mi = 0; mi < 4; ++mi)
#pragma unroll
        for (int ni = 0; ni < 4; ++ni) acc[mi][ni] = (f32x4)0.f;

    auto issue = [&](int kk, int buf) {
#pragma unroll
        for (int r = 0; r < 2; ++r) {
            int idx = r * 256 + tid;
            int prow = idx >> 2;
            int sub = ((idx & 3) - (prow >> 1)) & 3;  // swizzled k-group
            const bf16* gA = xb + ((size_t)(mbase + prow) << 8) + kk * 32 + (sub << 3);
            const bf16* gB = xb + ((size_t)(nbase + prow) << 8) + kk * 32 + (sub << 3);
            bf16* lA = As + buf * 4096 + ((r * 4 + wave) << 9);
            bf16* lB = Bs + buf * 4096 + ((r * 4 + wave) << 9);
            __builtin_amdgcn_global_load_lds((const GAS void*)gA, (LAS void*)lA, 16, 0, 0);
            __builtin_amdgcn_global_load_lds((const GAS void*)gB, (LAS void*)lB, 16, 0, 0);
        }
    };
    issue(0, 0);
    const int rslot = ((quad + (l15 >> 1)) & 3) * 8;
#pragma unroll
    for (int kk = 0; kk < 8; ++kk) {
        __syncthreads();
        if (kk < 7) issue(kk + 1, (kk + 1) & 1);
        int buf = kk & 1;
        bf16x8 af[4], bfr[4];
#pragma unroll
        for (int i = 0; i < 4; ++i) {
            af[i]  = *(const bf16x8*)(As + buf * 4096 + (wm * 64 + i * 16 + l15) * 32 + rslot);
            bfr[i] = *(const bf16x8*)(Bs + buf * 4096 + (wn * 64 + i * 16 + l15) * 32 + rslot);
        }
#pragma unroll
        for (int mi = 0; mi < 4; ++mi)
#pragma unroll
            for (int ni = 0; ni < 4; ++ni)
                acc[mi][ni] = __builtin_amdgcn_mfma_f32_16x16x32_bf16(af[mi], bfr[ni],
                                                                      acc[mi][ni], 0, 0, 0);
    }
}

// extw[j] = scale*(1 - exp(-(adr^2+(j-63)^2)/20.48)), j in [0,128) — wave-private
__device__ __forceinline__ void build_ext(float* extw, int lane, int adr, float scale) {
    float fr2 = (float)(adr * adr);
#pragma unroll
    for (int h = 0; h < 2; ++h) {
        int j = lane + h * 64;
        float d = (float)(j - 63);
        extw[j] = scale * (1.f - __expf(-(fr2 + d * d) * INV2S2));
    }
}

// per-lane register table e[dm][r], dm = mi-ni+3
__device__ __forceinline__ void load_etab(const float* extw_wave, int quad, int l15,
                                          float (&e)[7][4]) {
    const float* p = extw_wave + 63 + quad * 4 - l15;
#pragma unroll
    for (int dm = 0; dm < 7; ++dm)
#pragma unroll
        for (int r = 0; r < 4; ++r) e[dm][r] = p[(dm - 3) * 16 + r];
}

// ---------------- pass B: rowsum partials (+ optional fp16 p2 store) ----------------
// Base-2 log domain (HW-validated): p = s*log2e, sbuf holds 2p,
// lsm = -log2(rowsum), keys = 2p + lsm (= log2e * original key, same top-3).
// sbuf stores are REGULAR (R17 showed nt stores cost rowsum ~8.5us);
// topsel reads stay nontemporal.
__global__ __launch_bounds__(256) void corr_rowsum(const bf16* __restrict__ xnT,
                                                   const float* __restrict__ alpha_p,
                                                   float* __restrict__ rpart,
                                                   f16* __restrict__ sbuf,
                                                   int store_s2) {
    __shared__ __align__(16) bf16 SH[16384];
    bf16* As = SH;
    bf16* Bs = SH + 8192;
    int tid = threadIdx.x;
    int lin = blockIdx.x;
    int xcd = lin & 7;
    int b = xcd >> 1;
    int t = ((lin >> 3) << 1) + (xcd & 1);  // [0, 528)
    int mt, nt;
    decode_tri(t, mt, nt);
    int mbase = mt * 128, nbase = nt * 128;
    int wave = tid >> 6, lane = tid & 63;
    int wm = wave >> 1, wn = wave & 1, l15 = lane & 15, quad = lane >> 4;
    int rowi = (mbase + wm * 64) >> 6;
    int coli = (nbase + wn * 64) >> 6;
    int adr = rowi - coli; if (adr < 0) adr = -adr;
    float alpha2 = alpha_p[0] * LOG2E;

    f32x4 acc[4][4];
    gemm_tile(xnT + ((size_t)b << 20), mbase, nbase, As, Bs, acc);

    float* F = (float*)SH;
    float* ext  = F;              // [4][128] wave-private (dead As-buf0)
    float* rbuf = F + 512;        // [2][128]
    float* cbuf = F + 768;        // [2][128]
    build_ext(ext + wave * 128, lane, adr, alpha2);
    float e[7][4];
    load_etab(ext + wave * 128, quad, l15, e);

    const size_t tb = (size_t)(b * NTILE + t) * 16384;
    float colpart[4] = {0.f, 0.f, 0.f, 0.f};
#pragma unroll
    for (int mi = 0; mi < 4; ++mi) {
#pragma unroll
        for (int r = 0; r < 4; ++r) {
            float ssum = 0.f;
            float sv[4];
#pragma unroll
            for (int ni = 0; ni < 4; ++ni) {
                float p = e[mi - ni + 3][r] * acc[mi][ni][r];  // s*log2e
                sv[ni] = p;
                float ev = EXP2F(p);                            // = exp(s)
                ssum += ev;
                colpart[ni] += ev;
            }
            if (store_s2) {
                // p2 region (mi,r): 1024 halfs; lane writes 8B coalesced
                f16x4 pk;
#pragma unroll
                for (int ni = 0; ni < 4; ++ni) pk[ni] = (f16)(sv[ni] + sv[ni]);
                *(f16x4*)(sbuf + tb + (mi * 4 + r) * 1024 + tid * 4) = pk;
            }
            ssum += __shfl_xor(ssum, 1);
            ssum += __shfl_xor(ssum, 2);
            ssum += __shfl_xor(ssum, 4);
            ssum += __shfl_xor(ssum, 8);
            if (l15 == 0) rbuf[wn * 128 + wm * 64 + mi * 16 + quad * 4 + r] = ssum;
        }
    }
#pragma unroll
    for (int ni = 0; ni < 4; ++ni) {
        float c = colpart[ni];
        c += __shfl_xor(c, 16);
        c += __shfl_xor(c, 32);
        if (quad == 0) cbuf[wm * 128 + wn * 64 + ni * 16 + l15] = c;
    }
    __syncthreads();
    if (tid < 128) {
        rpart[(size_t)((b * 32 + mt) * 32 + nt) * 128 + tid] = rbuf[tid] + rbuf[128 + tid];
    } else if (mt != nt) {
        int j = tid - 128;
        rpart[(size_t)((b * 32 + nt) * 32 + mt) * 128 + j] = cbuf[j] + cbuf[128 + j];
    }
}

// ---------------- slot-reduce + reciprocal + negative log2 ----------------
__global__ __launch_bounds__(256) void corr_recip(const float* __restrict__ rpart,
                                                  float* __restrict__ ism,
                                                  float* __restrict__ lsm) {
    int i = blockIdx.x * 256 + threadIdx.x;
    if (i >= 4 * HW) return;
    int b = i >> 12, gr = i & 4095, s = gr >> 7, j = gr & 127;
    const float* base = rpart + (size_t)((b * 32 + s) * 32) * 128 + j;
    float sum = 0.f;
#pragma unroll
    for (int sl = 0; sl < 32; ++sl) sum += base[sl * 128];
    ism[i] = 1.0f / sum;
    lsm[i] = -log2f(sum);
}

// ================= shared epilogue for both topk variants =================
// keys[(mi*4+r)*4+ni] = 2p + per-dir log2 term; does dual-direction select+store.
__device__ __forceinline__ void topk_epilogue(int b, int mt, int nt,
                                              const float (&s2f)[16][4],
                                              const float (&lr)[4][4], const float (&lc)[4],
                                              float* mbuf, float* rtop,
                                              float* __restrict__ wtop,
                                              int tid, int wm, int wn, int l15, int quad) {
    // ---- column direction: top3 over rows for each tile column ----
#pragma unroll
    for (int ni = 0; ni < 4; ++ni) {
        float t0 = NEGINF, t1 = NEGINF, t2 = NEGINF;
#pragma unroll
        for (int mi = 0; mi < 4; ++mi) {
#pragma unroll
            for (int r = 0; r < 4; ++r) {
                float key = s2f[mi * 4 + r][ni] + lr[mi][r];
                ins3(key, t0, t1, t2);
            }
        }
#pragma unroll
        for (int d = 16; d <= 32; d <<= 1) {
            float s0 = __shfl_xor(t0, d);
            float s1 = __shfl_xor(t1, d);
            float s2 = __shfl_xor(t2, d);
            ins3(s0, t0, t1, t2);
            ins3(s1, t0, t1, t2);
            ins3(s2, t0, t1, t2);
        }
        if (quad == 0) {
            int cl = wn * 64 + ni * 16 + l15;
            mbuf[(wm * 128 + cl) * 3 + 0] = t0;
            mbuf[(wm * 128 + cl) * 3 + 1] = t1;
            mbuf[(wm * 128 + cl) * 3 + 2] = t2;
        }
    }
    __syncthreads();
    // ---- row direction (xc[c,n]=xc[n,c]): top3 over cols for each tile row ----
    if (mt != nt) {
#pragma unroll
        for (int mi = 0; mi < 4; ++mi) {
#pragma unroll
            for (int r = 0; r < 4; ++r) {
                float u0 = NEGINF, u1 = NEGINF, u2 = NEGINF;
#pragma unroll
                for (int ni = 0; ni < 4; ++ni) {
                    float key = s2f[mi * 4 + r][ni] + lc[ni];
                    ins3(key, u0, u1, u2);
                }
                {
                    float s0 = __shfl_xor(u0, 8);
                    float s1 = __shfl_xor(u1, 8);
                    float s2 = __shfl_xor(u2, 8);
                    ins3(s0, u0, u1, u2);
                    ins3(s1, u0, u1, u2);
                    ins3(s2, u0, u1, u2);
                }
                if (l15 < 8) {
                    int row = wm * 64 + mi * 16 + quad * 4 + r;
                    int slot = wn * 8 + l15;
                    float* q = rtop + row * 51 + slot * 3;
                    q[0] = u0; q[1] = u1; q[2] = u2;
                }
            }
        }
    }
    __syncthreads();
    if (tid < 128) {
        float t0 = mbuf[tid * 3], t1 = mbuf[tid * 3 + 1], t2 = mbuf[tid * 3 + 2];
        ins3(mbuf[(128 + tid) * 3 + 0], t0, t1, t2);
        ins3(mbuf[(128 + tid) * 3 + 1], t0, t1, t2);
        ins3(mbuf[(128 + tid) * 3 + 2], t0, t1, t2);
        size_t o = ((size_t)((b * 32 + nt) * 32 + mt) * 128 + tid) * 3;
        wtop[o] = t0;
        wtop[o + 1] = t1;
        wtop[o + 2] = t2;
        if (mt != nt) {
            float v0 = NEGINF, v1 = NEGINF, v2 = NEGINF;
            const float* q = rtop + tid * 51;
#pragma unroll
            for (int sl = 0; sl < 16; ++sl) {
                ins3(q[sl * 3 + 0], v0, v1, v2);
                ins3(q[sl * 3 + 1], v0, v1, v2);
                ins3(q[sl * 3 + 2], v0, v1, v2);
            }
            size_t o2 = ((size_t)((b * 32 + mt) * 32 + nt) * 128 + tid) * 3;
            wtop[o2] = v0;
            wtop[o2 + 1] = v1;
            wtop[o2 + 2] = v2;
        }
    }
}

// ---------------- pass C (fast): streaming selector over stored fp16 p2 ----------------
__global__ __launch_bounds__(256) void corr_topsel(const f16* __restrict__ sbuf,
                                                   const float* __restrict__ lsm,
                                                   float* __restrict__ wtop) {
    __shared__ float FS[7296];  // mbuf 768 | rtop 128*51
    float* mbuf = FS;
    float* rtop = FS + 768;
    int tid = threadIdx.x;
    int lin = blockIdx.x;
    int xcd = lin & 7;
    int b = xcd >> 1;
    int t = ((lin >> 3) << 1) + (xcd & 1);
    int mt, nt;
    decode_tri(t, mt, nt);
    int mbase = mt * 128, nbase = nt * 128;
    int wave = tid >> 6, lane = tid & 63;
    int wm = wave >> 1, wn = wave & 1, l15 = lane & 15, quad = lane >> 4;

    const size_t tb = (size_t)(b * NTILE + t) * 16384;
    float s2f[16][4];
#pragma unroll
    for (int k = 0; k < 16; ++k) {
        f16x4 hv = __builtin_nontemporal_load((const f16x4*)(sbuf + tb + k * 1024 + tid * 4));
#pragma unroll
        for (int ni = 0; ni < 4; ++ni) s2f[k][ni] = (float)hv[ni];
    }
    float lr[4][4];
#pragma unroll
    for (int mi = 0; mi < 4; ++mi)
#pragma unroll
        for (int r = 0; r < 4; ++r)
            lr[mi][r] = lsm[(b << 12) + mbase + wm * 64 + mi * 16 + quad * 4 + r];
    float lc[4];
#pragma unroll
    for (int ni = 0; ni < 4; ++ni)
        lc[ni] = lsm[(b << 12) + nbase + wn * 64 + ni * 16 + l15];

    topk_epilogue(b, mt, nt, s2f, lr, lc, mbuf, rtop, wtop, tid, wm, wn, l15, quad);
}

// ---------------- pass C (fallback): R9 full-GEMM topk ----------------
__global__ __launch_bounds__(256) void corr_topk(const bf16* __restrict__ xnT,
                                                 const float* __restrict__ alpha_p,
                                                 const float* __restrict__ lsm,
                                                 float* __restrict__ wtop) {
    __shared__ __align__(16) bf16 SH[16384];
    bf16* As = SH;
    bf16* Bs = SH + 8192;
    int tid = threadIdx.x;
    int lin = blockIdx.x;
    int xcd = lin & 7;
    int b = xcd >> 1;
    int t = ((lin >> 3) << 1) + (xcd & 1);
    int mt, nt;
    decode_tri(t, mt, nt);
    int mbase = mt * 128, nbase = nt * 128;
    int wave = tid >> 6, lane = tid & 63;
    int wm = wave >> 1, wn = wave & 1, l15 = lane & 15, quad = lane >> 4;
    int rowi = (mbase + wm * 64) >> 6;
    int coli = (nbase + wn * 64) >> 6;
    int adr = rowi - coli; if (adr < 0) adr = -adr;
    float a2 = 2.0f * alpha_p[0] * LOG2E;

    f32x4 acc[4][4];
    gemm_tile(xnT + ((size_t)b << 20), mbase, nbase, As, Bs, acc);

    float* F = (float*)SH;
    float* ext  = F;
    float* mbuf = F + 512;
    float* rtop = F + 1280;
    build_ext(ext + wave * 128, lane, adr, a2);
    float e[7][4];
    load_etab(ext + wave * 128, quad, l15, e);

    float s2f[16][4];
#pragma unroll
    for (int mi = 0; mi < 4; ++mi)
#pragma unroll
        for (int r = 0; r < 4; ++r)
#pragma unroll
            for (int ni = 0; ni < 4; ++ni)
                s2f[mi * 4 + r][ni] = e[mi - ni + 3][r] * acc[mi][ni][r];
    float lr[4][4];
#pragma unroll
    for (int mi = 0; mi < 4; ++mi)
#pragma unroll
        for (int r = 0; r < 4; ++r)
            lr[mi][r] = lsm[(b << 12) + mbase + wm * 64 + mi * 16 + quad * 4 + r];
    float lc[4];
#pragma unroll
    for (int ni = 0; ni < 4; ++ni)
        lc[ni] = lsm[(b << 12) + nbase + wn * 64 + ni * 16 + l15];

    __syncthreads();  // GEMM LDS reads done; mbuf/rtop reuse safe
    topk_epilogue(b, mt, nt, s2f, lr, lc, mbuf, rtop, wtop, tid, wm, wn, l15, quad);
}

// ---------------- final merge of 32 slot-partials per column; exp2 + column scale ------
__global__ __launch_bounds__(256) void corr_merge(const float* __restrict__ wtop,
                                                  const float* __restrict__ ism,
                                                  float* __restrict__ out) {
    int idx = blockIdx.x * 256 + threadIdx.x;
    if (idx >= 4 * HW) return;
    int b = idx >> 12, col = idx & 4095;
    int strip = col >> 7, j = col & 127;
    const float* base = wtop + ((size_t)((b * 32 + strip) * 32) * 128 + j) * 3;
    float t0 = NEGINF, t1 = NEGINF, t2 = NEGINF;
    for (int sl = 0; sl < 32; ++sl) {
        const float* q = base + (size_t)sl * 128 * 3;
        ins3(q[0], t0, t1, t2);
        ins3(q[1], t0, t1, t2);
        ins3(q[2], t0, t1, t2);
    }
    float ismc = ism[idx];
    out[((b * 3 + 0) << 12) + col] = EXP2F(t0) * ismc;
    out[((b * 3 + 1) << 12) + col] = EXP2F(t1) * ismc;
    out[((b * 3 + 2) << 12) + col] = EXP2F(t2) * ismc;
}

extern "C" void kernel_launch(void* const* d_in, const int* in_sizes, int n_in,
                              void* d_out, int out_size, void* d_ws, size_t ws_size,
                              hipStream_t stream) {
    const float* x = (const float*)d_in[0];
    const float* alpha = (const float*)d_in[1];
    float* out = (float*)d_out;
    char* ws = (char*)d_ws;
    bf16* xnT = (bf16*)ws;                                    // 8 MB
    float* ism = (float*)(ws + (8u << 20));                   // 64 KB
    float* lsm = (float*)(ws + (8u << 20) + (64u << 10));     // 64 KB
    float* rpart = (float*)(ws + (8u << 20) + (128u << 10));  // 2 MB (aliases wtop)
    float* wtop  = (float*)(ws + (8u << 20) + (128u << 10));  // 6 MB
    f16* sbuf = (f16*)(ws + (8u << 20) + (128u << 10) + (6u << 20));
    size_t need = (8u << 20) + (128u << 10) + (6u << 20) + (size_t)4 * NTILE * 16384 * 2;
    int fast = (ws_size >= need);

    corr_norm<<<256, 256, 0, stream>>>(x, xnT);
    corr_rowsum<<<NTILE * 4, 256, 0, stream>>>(xnT, alpha, rpart, sbuf, fast);
    corr_recip<<<64, 256, 0, stream>>>(rpart, ism, lsm);
    if (fast)
        corr_topsel<<<NTILE * 4, 256, 0, stream>>>(sbuf, lsm, wtop);
    else
        corr_topk<<<NTILE * 4, 256, 0, stream>>>(xnT, alpha, lsm, wtop);
    corr_merge<<<64, 256, 0, stream>>>(wtop, ism, out);
}

// Round 7
// 130.999 us; speedup vs baseline: 1.0423x; 1.0423x over previous
//
#include <hip/hip_runtime.h>
#include <hip/hip_bf16.h>
#include <math.h>

// Corr: B=4, C=256, H=W=64, HW=4096, TOPK=3, rat_s=0.05 -> sigma=3.2, 2*sigma^2=20.48
// s[m,n] = alpha * (1 - exp(-(dr^2+dc^2)/20.48)) * <xn_m, xn_n>  (symmetric)
// xc[m,n] = exp(2 s[m,n]) / (sm[m] sm[n]),  sm[m] = sum_n exp(s[m,n])
// out[b,k,col] = top-3 over m of xc[m,col]
//
// R1..R9/R13 (proven): XCD binding, log-domain topk, non-atomic partials,
//   k-slot swizzle, triangular dual-dir topk, single-GEMM + fp16 p2 sbuf.
// BANNED (measured): raw vmcnt barriers w/ LDS-DMA (R7), cooperative launch
//   (R10), spin barriers (R11), device fences (R12), per-lane direct-L2 MFMA
//   loads (R14, 87us).
//   R15: BK=64 NULL; +35% VALU NULL -> neither barrier-count nor VALU limits.
//   R16: 2-tiles/block WORSE (59.5) -> wall ~= residency x per-block latency.
//   R17/R18: nt-store/nt-load seesaw: nt stores shift ~8.5us rowsum<->downstream
//   (keep REGULAR stores + NT loads; both exposed-latency symptoms).
// R19 (this round): HALF-TILE rowsum. 64x128 blocks (grid 4224): residency was
//   pinned ~1.3 blocks/CU across all rounds; R16 showed 2x work/block hurts
//   proportionally -> test 0.5x. LDS 24KB (6 blocks/CU cap), acc[2][4],
//   epilogue halved, B-panel shared by adjacent half-blocks (same XCD).
//   sbuf composes the same 128^2 tile layout (topsel unchanged). rpart gets a
//   64-slot parity dim (each half writes full j-range, zeros outside its rows
//   -> every slot written exactly once, no init); recip sums 64.

#define HW 4096
#define CDIM 256
#define INV2S2 0.048828125f  // 1/20.48
#define NEGINF -1e30f
#define NTILE 528
#define LOG2E 1.4426950408889634f

#if defined(__has_builtin)
#  if __has_builtin(__builtin_amdgcn_exp2f)
#    define EXP2F(x) __builtin_amdgcn_exp2f(x)
#  else
#    define EXP2F(x) exp2f(x)
#  endif
#else
#  define EXP2F(x) exp2f(x)
#endif

typedef __bf16 bf16;
typedef _Float16 f16;
typedef __attribute__((ext_vector_type(8))) __bf16 bf16x8;
typedef __attribute__((ext_vector_type(4))) _Float16 f16x4;
typedef __attribute__((ext_vector_type(4))) float f32x4;

#define GAS __attribute__((address_space(1)))
#define LAS __attribute__((address_space(3)))

__device__ __forceinline__ void ins3(float v, float& t0, float& t1, float& t2) {
    // maintains t0>=t1>=t2; exact top-3 insert in 3 VALU ops (v_max + 2x v_med3)
    float n0 = fmaxf(t0, v);
    float n1 = __builtin_amdgcn_fmed3f(t0, t1, v);
    float n2 = __builtin_amdgcn_fmed3f(t1, t2, v);
    t0 = n0; t1 = n1; t2 = n2;
}

// triangular decode: t = mt*(mt+1)/2 + nt, nt <= mt
__device__ __forceinline__ void decode_tri(int t, int& mt, int& nt) {
    int m = (int)((sqrtf(8.f * (float)t + 1.f) - 1.f) * 0.5f);
    while ((m + 1) * (m + 2) / 2 <= t) ++m;
    while (m * (m + 1) / 2 > t) --m;
    mt = m;
    nt = t - m * (m + 1) / 2;
}

// ---------------- normalize + transpose to bf16 xnT[b][pixel][channel] ----------------
__global__ __launch_bounds__(256) void corr_norm(const float* __restrict__ x,
                                                 bf16* __restrict__ xnT) {
    __shared__ float red[4][64];
    __shared__ float invn[64];
    __shared__ __align__(16) bf16 T[64][264];  // 264 = 256 + 8 pad
    int tid = threadIdx.x;
    int pl = tid & 63, cg = tid >> 6;
    int P0 = blockIdx.x * 64;
    int P = P0 + pl;
    int b = P >> 12;
    int pix = P & 4095;
    const float* xb = x + ((size_t)(b * CDIM + cg * 64) << 12) + pix;
    float v[64];
    float ss = 0.f;
#pragma unroll
    for (int j = 0; j < 64; ++j) {
        v[j] = xb[(size_t)j << 12];
        ss += v[j] * v[j];
    }
    red[cg][pl] = ss;
    __syncthreads();
    if (tid < 64) {
        float s = red[0][tid] + red[1][tid] + red[2][tid] + red[3][tid];
        invn[tid] = 1.0f / fmaxf(sqrtf(s), 1e-12f);
    }
    __syncthreads();
    float inv = invn[pl];
#pragma unroll
    for (int j0 = 0; j0 < 64; j0 += 8) {
        bf16x8 pk;
#pragma unroll
        for (int j = 0; j < 8; ++j) pk[j] = (bf16)(v[j0 + j] * inv);
        *(bf16x8*)(&T[pl][cg * 64 + j0]) = pk;
    }
    __syncthreads();
#pragma unroll
    for (int it = 0; it < 8; ++it) {
        int p = it * 8 + (tid >> 5);
        int k = tid & 31;
        bf16x8 val = *(const bf16x8*)(&T[p][k * 8]);
        *(bf16x8*)(xnT + (size_t)(P0 + p) * CDIM + k * 8) = val;
    }
}

// extw[j] = scale*(1 - exp(-(adr^2+(j-63)^2)/20.48)), j in [0,128) — wave-private
__device__ __forceinline__ void build_ext(float* extw, int lane, int adr, float scale) {
    float fr2 = (float)(adr * adr);
#pragma unroll
    for (int h = 0; h < 2; ++h) {
        int j = lane + h * 64;
        float d = (float)(j - 63);
        extw[j] = scale * (1.f - __expf(-(fr2 + d * d) * INV2S2));
    }
}

// per-lane register table e[dm][r], dm = mi-ni+3 (full 128x128 variant)
__device__ __forceinline__ void load_etab(const float* extw_wave, int quad, int l15,
                                          float (&e)[7][4]) {
    const float* p = extw_wave + 63 + quad * 4 - l15;
#pragma unroll
    for (int dm = 0; dm < 7; ++dm)
#pragma unroll
        for (int r = 0; r < 4; ++r) e[dm][r] = p[(dm - 3) * 16 + r];
}

// ---------------- pass B: rowsum partials, HALF-TILE blocks (64x128) ----------------
// Base-2 log domain: p = s*log2e, sbuf holds 2p, lsm = -log2(rowsum).
// Block (b, t, h): rows [mt*128+h*64, +64), cols [nt*128, +128).
// Two half-blocks compose the exact 128^2 sbuf tile layout topsel expects.
// rpart: [b][strip s][64 slots][128 j]; rows -> slot nt*2+h (zeros outside own
// rows), cols -> slot mt*2+h; every slot written exactly once.
__global__ __launch_bounds__(256) void corr_rowsum(const bf16* __restrict__ xnT,
                                                   const float* __restrict__ alpha_p,
                                                   float* __restrict__ rpart,
                                                   f16* __restrict__ sbuf,
                                                   int store_s2) {
    __shared__ __align__(16) bf16 SH[12288];  // 24KB: As 2x2048 | Bs 2x4096
    bf16* As = SH;
    bf16* Bs = SH + 4096;
    int tid = threadIdx.x;
    int lin = blockIdx.x;
    int xcd = lin & 7;
    int b = xcd >> 1;
    int v = lin >> 3;                        // [0, 528)
    int h = v & 1;                           // half-tile (row half)
    int t = ((v >> 1) << 1) + (xcd & 1);     // [0, 528)
    int mt, nt;
    decode_tri(t, mt, nt);
    int mbase = mt * 128 + h * 64;           // 64-row half
    int nbase = nt * 128;
    int wave = tid >> 6, lane = tid & 63;
    int wm = wave >> 1, wn = wave & 1, l15 = lane & 15, quad = lane >> 4;
    int rowi = mbase >> 6;                   // pixel row of the block's 64 m's
    int coli = (nbase + wn * 64) >> 6;
    int adr = rowi - coli; if (adr < 0) adr = -adr;
    float alpha2 = alpha_p[0] * LOG2E;
    const bf16* xb = xnT + ((size_t)b << 20);
    const int rslot = ((quad + (l15 >> 1)) & 3) * 8;

    auto issue = [&](int kk, int buf) {
        {   // A: 64 rows x 32k (256 DMA ops, 1/thread)
            int idx = tid;
            int prow = idx >> 2;
            int sub = ((idx & 3) - (prow >> 1)) & 3;
            const bf16* gA = xb + ((size_t)(mbase + prow) << 8) + kk * 32 + (sub << 3);
            bf16* lA = As + buf * 2048 + (wave << 9);
            __builtin_amdgcn_global_load_lds((const GAS void*)gA, (LAS void*)lA, 16, 0, 0);
        }
#pragma unroll
        for (int r = 0; r < 2; ++r) {  // B: 128 rows x 32k (512 DMA ops)
            int idx = r * 256 + tid;
            int prow = idx >> 2;
            int sub = ((idx & 3) - (prow >> 1)) & 3;
            const bf16* gB = xb + ((size_t)(nbase + prow) << 8) + kk * 32 + (sub << 3);
            bf16* lB = Bs + buf * 4096 + ((r * 4 + wave) << 9);
            __builtin_amdgcn_global_load_lds((const GAS void*)gB, (LAS void*)lB, 16, 0, 0);
        }
    };

    f32x4 acc[2][4];
#pragma unroll
    for (int mi = 0; mi < 2; ++mi)
#pragma unroll
        for (int ni = 0; ni < 4; ++ni) acc[mi][ni] = (f32x4)0.f;

    issue(0, 0);
#pragma unroll
    for (int kk = 0; kk < 8; ++kk) {
        __syncthreads();
        if (kk < 7) issue(kk + 1, (kk + 1) & 1);
        int buf = kk & 1;
        bf16x8 af[2], bfr[4];
#pragma unroll
        for (int i = 0; i < 2; ++i)
            af[i] = *(const bf16x8*)(As + buf * 2048 + (wm * 32 + i * 16 + l15) * 32 + rslot);
#pragma unroll
        for (int i = 0; i < 4; ++i)
            bfr[i] = *(const bf16x8*)(Bs + buf * 4096 + (wn * 64 + i * 16 + l15) * 32 + rslot);
#pragma unroll
        for (int mi = 0; mi < 2; ++mi)
#pragma unroll
            for (int ni = 0; ni < 4; ++ni)
                acc[mi][ni] = __builtin_amdgcn_mfma_f32_16x16x32_bf16(af[mi], bfr[ni],
                                                                      acc[mi][ni], 0, 0, 0);
    }

    // epilogue scratch aliases As buf0 (dead: kk=7 read buf1; barrier fenced buf0)
    float* F = (float*)SH;        // 1024 floats = 4KB = As buf0
    float* ext  = F;              // [4][128] wave-private... (512 floats)
    float* rbuf = F + 512;        // [2][64]
    float* cbuf = F + 640;        // [2][128]
    build_ext(ext + wave * 128, lane, adr, alpha2);
    // e[dmi][r], dmi = mi-ni+3 in [0,4]; j = 63 + wm*32 + (mi-ni)*16 + quad*4 + r - l15
    float e[5][4];
    {
        const float* p = ext + wave * 128 + 63 + wm * 32 + quad * 4 - l15;
#pragma unroll
        for (int dm = 0; dm < 5; ++dm)
#pragma unroll
            for (int r = 0; r < 4; ++r) e[dm][r] = p[(dm - 3) * 16 + r];
    }

    const size_t tb = (size_t)(b * NTILE + t) * 16384;
    float colpart[4] = {0.f, 0.f, 0.f, 0.f};
#pragma unroll
    for (int mi = 0; mi < 2; ++mi) {
#pragma unroll
        for (int r = 0; r < 4; ++r) {
            float ssum = 0.f;
            float sv[4];
#pragma unroll
            for (int ni = 0; ni < 4; ++ni) {
                float p = e[mi - ni + 3][r] * acc[mi][ni][r];  // s*log2e
                sv[ni] = p;
                float ev = EXP2F(p);                            // = exp(s)
                ssum += ev;
                colpart[ni] += ev;
            }
            if (store_s2) {
                // topsel frame: k2 = (wm*2+mi)*4+r, thread slot (h*2+wn)*64+lane
                f16x4 pk;
#pragma unroll
                for (int ni = 0; ni < 4; ++ni) pk[ni] = (f16)(sv[ni] + sv[ni]);
                *(f16x4*)(sbuf + tb + ((wm * 2 + mi) * 4 + r) * 1024 +
                          ((h * 2 + wn) * 64 + lane) * 4) = pk;
            }
            ssum += __shfl_xor(ssum, 1);
            ssum += __shfl_xor(ssum, 2);
            ssum += __shfl_xor(ssum, 4);
            ssum += __shfl_xor(ssum, 8);
            if (l15 == 0) rbuf[wn * 64 + wm * 32 + mi * 16 + quad * 4 + r] = ssum;
        }
    }
#pragma unroll
    for (int ni = 0; ni < 4; ++ni) {
        float c = colpart[ni];
        c += __shfl_xor(c, 16);
        c += __shfl_xor(c, 32);
        if (quad == 0) cbuf[wm * 128 + wn * 64 + ni * 16 + l15] = c;
    }
    __syncthreads();
    if (tid < 128) {
        int j = tid;
        float vr = ((j >> 6) == h) ? (rbuf[j & 63] + rbuf[64 + (j & 63)]) : 0.f;
        rpart[(size_t)((b * 32 + mt) * 64 + nt * 2 + h) * 128 + j] = vr;
    } else if (mt != nt) {
        int j = tid - 128;
        rpart[(size_t)((b * 32 + nt) * 64 + mt * 2 + h) * 128 + j] = cbuf[j] + cbuf[128 + j];
    }
}

// ---------------- slot-reduce (64 slots) + reciprocal + negative log2 ----------------
__global__ __launch_bounds__(256) void corr_recip(const float* __restrict__ rpart,
                                                  float* __restrict__ ism,
                                                  float* __restrict__ lsm) {
    int i = blockIdx.x * 256 + threadIdx.x;
    if (i >= 4 * HW) return;
    int b = i >> 12, gr = i & 4095, s = gr >> 7, j = gr & 127;
    const float* base = rpart + (size_t)((b * 32 + s) * 64) * 128 + j;
    float sum = 0.f;
#pragma unroll
    for (int sl = 0; sl < 64; ++sl) sum += base[sl * 128];
    ism[i] = 1.0f / sum;
    lsm[i] = -log2f(sum);
}

// ================= shared epilogue for both topk variants =================
// keys[(mi*4+r)*4+ni] = 2p + per-dir log2 term; does dual-direction select+store.
__device__ __forceinline__ void topk_epilogue(int b, int mt, int nt,
                                              const float (&s2f)[16][4],
                                              const float (&lr)[4][4], const float (&lc)[4],
                                              float* mbuf, float* rtop,
                                              float* __restrict__ wtop,
                                              int tid, int wm, int wn, int l15, int quad) {
    // ---- column direction: top3 over rows for each tile column ----
#pragma unroll
    for (int ni = 0; ni < 4; ++ni) {
        float t0 = NEGINF, t1 = NEGINF, t2 = NEGINF;
#pragma unroll
        for (int mi = 0; mi < 4; ++mi) {
#pragma unroll
            for (int r = 0; r < 4; ++r) {
                float key = s2f[mi * 4 + r][ni] + lr[mi][r];
                ins3(key, t0, t1, t2);
            }
        }
#pragma unroll
        for (int d = 16; d <= 32; d <<= 1) {
            float s0 = __shfl_xor(t0, d);
            float s1 = __shfl_xor(t1, d);
            float s2 = __shfl_xor(t2, d);
            ins3(s0, t0, t1, t2);
            ins3(s1, t0, t1, t2);
            ins3(s2, t0, t1, t2);
        }
        if (quad == 0) {
            int cl = wn * 64 + ni * 16 + l15;
            mbuf[(wm * 128 + cl) * 3 + 0] = t0;
            mbuf[(wm * 128 + cl) * 3 + 1] = t1;
            mbuf[(wm * 128 + cl) * 3 + 2] = t2;
        }
    }
    __syncthreads();
    // ---- row direction (xc[c,n]=xc[n,c]): top3 over cols for each tile row ----
    if (mt != nt) {
#pragma unroll
        for (int mi = 0; mi < 4; ++mi) {
#pragma unroll
            for (int r = 0; r < 4; ++r) {
                float u0 = NEGINF, u1 = NEGINF, u2 = NEGINF;
#pragma unroll
                for (int ni = 0; ni < 4; ++ni) {
                    float key = s2f[mi * 4 + r][ni] + lc[ni];
                    ins3(key, u0, u1, u2);
                }
                {
                    float s0 = __shfl_xor(u0, 8);
                    float s1 = __shfl_xor(u1, 8);
                    float s2 = __shfl_xor(u2, 8);
                    ins3(s0, u0, u1, u2);
                    ins3(s1, u0, u1, u2);
                    ins3(s2, u0, u1, u2);
                }
                if (l15 < 8) {
                    int row = wm * 64 + mi * 16 + quad * 4 + r;
                    int slot = wn * 8 + l15;
                    float* q = rtop + row * 51 + slot * 3;
                    q[0] = u0; q[1] = u1; q[2] = u2;
                }
            }
        }
    }
    __syncthreads();
    if (tid < 128) {
        float t0 = mbuf[tid * 3], t1 = mbuf[tid * 3 + 1], t2 = mbuf[tid * 3 + 2];
        ins3(mbuf[(128 + tid) * 3 + 0], t0, t1, t2);
        ins3(mbuf[(128 + tid) * 3 + 1], t0, t1, t2);
        ins3(mbuf[(128 + tid) * 3 + 2], t0, t1, t2);
        size_t o = ((size_t)((b * 32 + nt) * 32 + mt) * 128 + tid) * 3;
        wtop[o] = t0;
        wtop[o + 1] = t1;
        wtop[o + 2] = t2;
        if (mt != nt) {
            float v0 = NEGINF, v1 = NEGINF, v2 = NEGINF;
            const float* q = rtop + tid * 51;
#pragma unroll
            for (int sl = 0; sl < 16; ++sl) {
                ins3(q[sl * 3 + 0], v0, v1, v2);
                ins3(q[sl * 3 + 1], v0, v1, v2);
                ins3(q[sl * 3 + 2], v0, v1, v2);
            }
            size_t o2 = ((size_t)((b * 32 + mt) * 32 + nt) * 128 + tid) * 3;
            wtop[o2] = v0;
            wtop[o2 + 1] = v1;
            wtop[o2 + 2] = v2;
        }
    }
}

// ---------------- pass C (fast): streaming selector over stored fp16 p2 ----------------
__global__ __launch_bounds__(256) void corr_topsel(const f16* __restrict__ sbuf,
                                                   const float* __restrict__ lsm,
                                                   float* __restrict__ wtop) {
    __shared__ float FS[7296];  // mbuf 768 | rtop 128*51
    float* mbuf = FS;
    float* rtop = FS + 768;
    int tid = threadIdx.x;
    int lin = blockIdx.x;
    int xcd = lin & 7;
    int b = xcd >> 1;
    int t = ((lin >> 3) << 1) + (xcd & 1);
    int mt, nt;
    decode_tri(t, mt, nt);
    int mbase = mt * 128, nbase = nt * 128;
    int wave = tid >> 6, lane = tid & 63;
    int wm = wave >> 1, wn = wave & 1, l15 = lane & 15, quad = lane >> 4;

    const size_t tb = (size_t)(b * NTILE + t) * 16384;
    float s2f[16][4];
#pragma unroll
    for (int k = 0; k < 16; ++k) {
        f16x4 hv = __builtin_nontemporal_load((const f16x4*)(sbuf + tb + k * 1024 + tid * 4));
#pragma unroll
        for (int ni = 0; ni < 4; ++ni) s2f[k][ni] = (float)hv[ni];
    }
    float lr[4][4];
#pragma unroll
    for (int mi = 0; mi < 4; ++mi)
#pragma unroll
        for (int r = 0; r < 4; ++r)
            lr[mi][r] = lsm[(b << 12) + mbase + wm * 64 + mi * 16 + quad * 4 + r];
    float lc[4];
#pragma unroll
    for (int ni = 0; ni < 4; ++ni)
        lc[ni] = lsm[(b << 12) + nbase + wn * 64 + ni * 16 + l15];

    topk_epilogue(b, mt, nt, s2f, lr, lc, mbuf, rtop, wtop, tid, wm, wn, l15, quad);
}

// ---------------- pass C (fallback): full-GEMM topk (proven 128^2 core) ----------------
__global__ __launch_bounds__(256) void corr_topk(const bf16* __restrict__ xnT,
                                                 const float* __restrict__ alpha_p,
                                                 const float* __restrict__ lsm,
                                                 float* __restrict__ wtop) {
    __shared__ __align__(16) bf16 SH[16384];
    bf16* As = SH;
    bf16* Bs = SH + 8192;
    int tid = threadIdx.x;
    int lin = blockIdx.x;
    int xcd = lin & 7;
    int b = xcd >> 1;
    int t = ((lin >> 3) << 1) + (xcd & 1);
    int mt, nt;
    decode_tri(t, mt, nt);
    int mbase = mt * 128, nbase = nt * 128;
    int wave = tid >> 6, lane = tid & 63;
    int wm = wave >> 1, wn = wave & 1, l15 = lane & 15, quad = lane >> 4;
    int rowi = (mbase + wm * 64) >> 6;
    int coli = (nbase + wn * 64) >> 6;
    int adr = rowi - coli; if (adr < 0) adr = -adr;
    float a2 = 2.0f * alpha_p[0] * LOG2E;
    const bf16* xb = xnT + ((size_t)b << 20);
    const int rslot = ((quad + (l15 >> 1)) & 3) * 8;

    auto issue = [&](int kk, int buf) {
#pragma unroll
        for (int r = 0; r < 2; ++r) {
            int idx = r * 256 + tid;
            int prow = idx >> 2;
            int sub = ((idx & 3) - (prow >> 1)) & 3;
            const bf16* gA = xb + ((size_t)(mbase + prow) << 8) + kk * 32 + (sub << 3);
            const bf16* gB = xb + ((size_t)(nbase + prow) << 8) + kk * 32 + (sub << 3);
            bf16* lA = As + buf * 4096 + ((r * 4 + wave) << 9);
            bf16* lB = Bs + buf * 4096 + ((r * 4 + wave) << 9);
            __builtin_amdgcn_global_load_lds((const GAS void*)gA, (LAS void*)lA, 16, 0, 0);
            __builtin_amdgcn_global_load_lds((const GAS void*)gB, (LAS void*)lB, 16, 0, 0);
        }
    };

    f32x4 acc[4][4];
#pragma unroll
    for (int mi = 0; mi < 4; ++mi)
#pragma unroll
        for (int ni = 0; ni < 4; ++ni) acc[mi][ni] = (f32x4)0.f;
    issue(0, 0);
#pragma unroll
    for (int kk = 0; kk < 8; ++kk) {
        __syncthreads();
        if (kk < 7) issue(kk + 1, (kk + 1) & 1);
        int buf = kk & 1;
        bf16x8 af[4], bfr[4];
#pragma unroll
        for (int i = 0; i < 4; ++i) {
            af[i]  = *(const bf16x8*)(As + buf * 4096 + (wm * 64 + i * 16 + l15) * 32 + rslot);
            bfr[i] = *(const bf16x8*)(Bs + buf * 4096 + (wn * 64 + i * 16 + l15) * 32 + rslot);
        }
#pragma unroll
        for (int mi = 0; mi < 4; ++mi)
#pragma unroll
            for (int ni = 0; ni < 4; ++ni)
                acc[mi][ni] = __builtin_amdgcn_mfma_f32_16x16x32_bf16(af[mi], bfr[ni],
                                                                      acc[mi][ni], 0, 0, 0);
    }

    float* Fh = (float*)SH;  // alias into As buf0 (dead after last K-step)
    float* ext  = Fh;
    float* mbuf = Fh + 512;
    float* rtop = Fh + 1280;
    build_ext(ext + wave * 128, lane, adr, a2);
    float e[7][4];
    load_etab(ext + wave * 128, quad, l15, e);

    float s2f[16][4];
#pragma unroll
    for (int mi = 0; mi < 4; ++mi)
#pragma unroll
        for (int r = 0; r < 4; ++r)
#pragma unroll
            for (int ni = 0; ni < 4; ++ni)
                s2f[mi * 4 + r][ni] = e[mi - ni + 3][r] * acc[mi][ni][r];
    float lr[4][4];
#pragma unroll
    for (int mi = 0; mi < 4; ++mi)
#pragma unroll
        for (int r = 0; r < 4; ++r)
            lr[mi][r] = lsm[(b << 12) + mbase + wm * 64 + mi * 16 + quad * 4 + r];
    float lc[4];
#pragma unroll
    for (int ni = 0; ni < 4; ++ni)
        lc[ni] = lsm[(b << 12) + nbase + wn * 64 + ni * 16 + l15];

    __syncthreads();  // GEMM LDS reads done; mbuf/rtop reuse safe
    topk_epilogue(b, mt, nt, s2f, lr, lc, mbuf, rtop, wtop, tid, wm, wn, l15, quad);
}

// ---------------- final merge of 32 slot-partials per column; exp2 + column scale ------
__global__ __launch_bounds__(256) void corr_merge(const float* __restrict__ wtop,
                                                  const float* __restrict__ ism,
                                                  float* __restrict__ out) {
    int idx = blockIdx.x * 256 + threadIdx.x;
    if (idx >= 4 * HW) return;
    int b = idx >> 12, col = idx & 4095;
    int strip = col >> 7, j = col & 127;
    const float* base = wtop + ((size_t)((b * 32 + strip) * 32) * 128 + j) * 3;
    float t0 = NEGINF, t1 = NEGINF, t2 = NEGINF;
    for (int sl = 0; sl < 32; ++sl) {
        const float* q = base + (size_t)sl * 128 * 3;
        ins3(q[0], t0, t1, t2);
        ins3(q[1], t0, t1, t2);
        ins3(q[2], t0, t1, t2);
    }
    float ismc = ism[idx];
    out[((b * 3 + 0) << 12) + col] = EXP2F(t0) * ismc;
    out[((b * 3 + 1) << 12) + col] = EXP2F(t1) * ismc;
    out[((b * 3 + 2) << 12) + col] = EXP2F(t2) * ismc;
}

extern "C" void kernel_launch(void* const* d_in, const int* in_sizes, int n_in,
                              void* d_out, int out_size, void* d_ws, size_t ws_size,
                              hipStream_t stream) {
    const float* x = (const float*)d_in[0];
    const float* alpha = (const float*)d_in[1];
    float* out = (float*)d_out;
    char* ws = (char*)d_ws;
    bf16* xnT = (bf16*)ws;                                    // 8 MB
    float* ism = (float*)(ws + (8u << 20));                   // 64 KB
    float* lsm = (float*)(ws + (8u << 20) + (64u << 10));     // 64 KB
    float* rpart = (float*)(ws + (8u << 20) + (128u << 10));  // 4 MB (aliases wtop)
    float* wtop  = (float*)(ws + (8u << 20) + (128u << 10));  // 6 MB
    f16* sbuf = (f16*)(ws + (8u << 20) + (128u << 10) + (6u << 20));
    size_t need = (8u << 20) + (128u << 10) + (6u << 20) + (size_t)4 * NTILE * 16384 * 2;
    int fast = (ws_size >= need);

    corr_norm<<<256, 256, 0, stream>>>(x, xnT);
    corr_rowsum<<<NTILE * 8, 256, 0, stream>>>(xnT, alpha, rpart, sbuf, fast);
    corr_recip<<<64, 256, 0, stream>>>(rpart, ism, lsm);
    if (fast)
        corr_topsel<<<NTILE * 4, 256, 0, stream>>>(sbuf, lsm, wtop);
    else
        corr_topk<<<NTILE * 4, 256, 0, stream>>>(xnT, alpha, lsm, wtop);
    corr_merge<<<64, 256, 0, stream>>>(wtop, ism, out);
}